// Round 5
// baseline (378.221 us; speedup 1.0000x reference)
//
#include <hip/hip_runtime.h>
#include <hip/hip_bf16.h>
#include <math.h>

#define BB 64
#define TT 4096
#define II 128
#define HH 256
#define LC 128           // chunk length
#define NC 32            // chunks = TT/LC
#define NCH 4            // chunks per k1 block

typedef __attribute__((ext_vector_type(8))) short short8;   // 8 bf16
typedef __attribute__((ext_vector_type(4))) float f32x4;

__device__ inline ushort f2b(float f) {
    __hip_bfloat16 h = __float2bfloat16(f);
    return *reinterpret_cast<ushort*>(&h);
}
__device__ inline float b2f(ushort u) {
    union { unsigned u; float f; } c; c.u = ((unsigned)u) << 16; return c.f;
}

// ---------------- K0: tables ----------------
__global__ __launch_bounds__(256) void k0_tables(
    const float* __restrict__ Wd, const float* __restrict__ bd,
    const float* __restrict__ Wo, const float* __restrict__ tau,
    ushort* __restrict__ Wdb, ushort* __restrict__ Vt,
    float* __restrict__ ApowT, float* __restrict__ alphas,
    float* __restrict__ mb, float* __restrict__ ybias)
{
    int idx = blockIdx.x * 256 + threadIdx.x;
    Wdb[idx] = f2b(Wd[idx]);                     // [h][i] bf16
    {
        int d = idx >> 8, h = idx & 255;         // d/k in 0..127, h in 0..255
        float a = 1.0f / (1.0f + expf(-tau[h]));
        float l2a = log2f(a);
        Vt[idx]    = f2b(Wo[h] * (1.0f - a) * exp2f((float)d * l2a));  // Vt[d][h]
        ApowT[idx] = exp2f((float)(d + 1) * l2a);                      // ApowT[k][h]=a^(k+1)
    }
    if (idx < HH) {
        float a = 1.0f / (1.0f + expf(-tau[idx]));
        alphas[idx] = a;
        mb[idx] = bd[idx] * (1.0f - exp2f(128.0f * log2f(a)));
    }
    if (idx < LC) {
        float s = 0.0f;
        for (int h = 0; h < HH; ++h) {
            float a = 1.0f / (1.0f + expf(-tau[h]));
            s += Wo[h] * bd[h] * (1.0f - exp2f((float)(idx + 1) * log2f(a)));
        }
        ybias[idx] = s;
    }
}

// ---------------- K1: fused, 4 chunks/block, pipelined ----------------
// grid = 512 blocks x 512 threads (exactly 2 blocks/CU resident all kernel)
// LDS: reg0 [0,34816):      As[t][i] (128x136 u16)  == curSb (h 128..255) == Ps rows 0..63
//      reg1 [34816,69632):  curSa (h 0..127)        == Ps rows 64..127
//      mp   [69632,+2048), psum [71680,+2048)
__global__ __launch_bounds__(512, 4) void k1_fused(
    const float* __restrict__ x, const ushort* __restrict__ Wdb,
    const ushort* __restrict__ Vt, const float* __restrict__ alphas,
    const float* __restrict__ mb, const float* __restrict__ ApowT,
    float* __restrict__ ypart, float* __restrict__ Mstate)
{
    __shared__ __align__(16) char smem[73728];
    ushort* reg0 = reinterpret_cast<ushort*>(smem);            // As / curSb
    ushort* reg1 = reinterpret_cast<ushort*>(smem + 34816);    // curSa
    float*  Ps   = reinterpret_cast<float*>(smem);             // stride 136 f32, 128 rows
    float*  mp   = reinterpret_cast<float*>(smem + 69632);
    float*  psum = reinterpret_cast<float*>(smem + 71680);

    const int b = blockIdx.x >> 3, q = blockIdx.x & 7;
    const int tid = threadIdx.x;
    const int lane = tid & 63, w = tid >> 6;
    const int l15 = lane & 15, quad = lane >> 4;

    const int hg = w & 3, th = w >> 2;     // MFMA1: h-group (32), t-half (64)
    const int dg = w & 3, sh2 = w >> 2;    // MFMA2: d-group (32), s-half (64)
    const int hsc = tid & 255, shalf = tid >> 8;   // scan role

    // hoisted per-thread constants
    const float a_sc = alphas[hsc], oma_sc = 1.0f - a_sc;
    float a64 = 0.f, mbv = 0.f;
    if (tid < HH) { a64 = ApowT[63 * 256 + tid]; mbv = mb[tid]; }

    // prologue: prefetch chunk 0 x-tile into registers
    const float4* xg0 = reinterpret_cast<const float4*>(x + ((size_t)b * TT + q * 512) * II);
    float4 xp[8];
#pragma unroll
    for (int it = 0; it < 8; ++it) xp[it] = xg0[it * 512 + tid];

    for (int ci = 0; ci < NCH; ++ci) {
        // ---- P0: write As[t][i] from prefetched regs ----
#pragma unroll
        for (int it = 0; it < 8; ++it) {
            int idx = it * 512 + tid;
            int t = idx >> 5, i4 = idx & 31;
            ushort4 u;
            u.x = f2b(xp[it].x); u.y = f2b(xp[it].y);
            u.z = f2b(xp[it].z); u.w = f2b(xp[it].w);
            *reinterpret_cast<ushort4*>(&reg0[t * 136 + i4 * 4]) = u;
        }
        __syncthreads();   // B0: As visible
        // prefetch next chunk
        if (ci < NCH - 1) {
#pragma unroll
            for (int it = 0; it < 8; ++it)
                xp[it] = xg0[(ci + 1) * 4096 + it * 512 + tid];
        }

        // ---- P1: MFMA1 half0 (h 0..127): C[h,t] = Wd @ x^T ----
        {
            f32x4 acc1[2][4];
#pragma unroll
            for (int mt = 0; mt < 2; ++mt)
#pragma unroll
                for (int nt = 0; nt < 4; ++nt) acc1[mt][nt] = (f32x4){0.f,0.f,0.f,0.f};
#pragma unroll
            for (int kt = 0; kt < 4; ++kt) {
                short8 af0 = *reinterpret_cast<const short8*>(
                    &Wdb[(size_t)(hg * 32 + l15) * II + kt * 32 + quad * 8]);
                short8 af1 = *reinterpret_cast<const short8*>(
                    &Wdb[(size_t)(hg * 32 + 16 + l15) * II + kt * 32 + quad * 8]);
#pragma unroll
                for (int nt = 0; nt < 4; ++nt) {
                    short8 bf = *reinterpret_cast<const short8*>(
                        &reg0[(th * 64 + nt * 16 + l15) * 136 + kt * 32 + quad * 8]);
                    acc1[0][nt] = __builtin_amdgcn_mfma_f32_16x16x32_bf16(af0, bf, acc1[0][nt], 0, 0, 0);
                    acc1[1][nt] = __builtin_amdgcn_mfma_f32_16x16x32_bf16(af1, bf, acc1[1][nt], 0, 0, 0);
                }
            }
            // write curSa (reg1) — write-only region, no barrier needed
#pragma unroll
            for (int mt = 0; mt < 2; ++mt)
#pragma unroll
                for (int nt = 0; nt < 4; ++nt) {
                    int t = th * 64 + nt * 16 + l15;
                    int hc = hg * 32 + mt * 16 + quad * 4;
                    ushort4 u;
                    u.x = f2b(acc1[mt][nt][0]); u.y = f2b(acc1[mt][nt][1]);
                    u.z = f2b(acc1[mt][nt][2]); u.w = f2b(acc1[mt][nt][3]);
                    *reinterpret_cast<ushort4*>(&reg1[t * 136 + hc]) = u;
                }
        }
        // ---- MFMA1 half1 (h 128..255) ----
        {
            f32x4 acc1[2][4];
#pragma unroll
            for (int mt = 0; mt < 2; ++mt)
#pragma unroll
                for (int nt = 0; nt < 4; ++nt) acc1[mt][nt] = (f32x4){0.f,0.f,0.f,0.f};
#pragma unroll
            for (int kt = 0; kt < 4; ++kt) {
                short8 af0 = *reinterpret_cast<const short8*>(
                    &Wdb[(size_t)(128 + hg * 32 + l15) * II + kt * 32 + quad * 8]);
                short8 af1 = *reinterpret_cast<const short8*>(
                    &Wdb[(size_t)(128 + hg * 32 + 16 + l15) * II + kt * 32 + quad * 8]);
#pragma unroll
                for (int nt = 0; nt < 4; ++nt) {
                    short8 bf = *reinterpret_cast<const short8*>(
                        &reg0[(th * 64 + nt * 16 + l15) * 136 + kt * 32 + quad * 8]);
                    acc1[0][nt] = __builtin_amdgcn_mfma_f32_16x16x32_bf16(af0, bf, acc1[0][nt], 0, 0, 0);
                    acc1[1][nt] = __builtin_amdgcn_mfma_f32_16x16x32_bf16(af1, bf, acc1[1][nt], 0, 0, 0);
                }
            }
            __syncthreads();   // B1: all As reads done (curSb overwrites As)
#pragma unroll
            for (int mt = 0; mt < 2; ++mt)
#pragma unroll
                for (int nt = 0; nt < 4; ++nt) {
                    int t = th * 64 + nt * 16 + l15;
                    int hc = hg * 32 + mt * 16 + quad * 4;
                    ushort4 u;
                    u.x = f2b(acc1[mt][nt][0]); u.y = f2b(acc1[mt][nt][1]);
                    u.z = f2b(acc1[mt][nt][2]); u.w = f2b(acc1[mt][nt][3]);
                    *reinterpret_cast<ushort4*>(&reg0[t * 136 + hc]) = u;
                }
        }
        __syncthreads();   // B2: cur (both halves) visible

        // ---- P3: scan partials + MFMA2 ----
        {
            const ushort* cbuf = (hsc < 128) ? reg1 : reg0;
            const int hoff = hsc & 127;
            float M = 0.0f;
#pragma unroll 8
            for (int i = 0; i < 64; ++i)
                M = fmaf(a_sc, M, oma_sc * b2f(cbuf[(shalf * 64 + i) * 136 + hoff]));
            mp[shalf * 256 + hsc] = M;
        }
        f32x4 acc2[2][4];
#pragma unroll
        for (int mt = 0; mt < 2; ++mt)
#pragma unroll
            for (int nt = 0; nt < 4; ++nt) acc2[mt][nt] = (f32x4){0.f,0.f,0.f,0.f};
#pragma unroll
        for (int kk = 0; kk < 8; ++kk) {
            short8 a20 = *reinterpret_cast<const short8*>(
                &Vt[(size_t)(dg * 32 + l15) * HH + kk * 32 + quad * 8]);
            short8 a21 = *reinterpret_cast<const short8*>(
                &Vt[(size_t)(dg * 32 + 16 + l15) * HH + kk * 32 + quad * 8]);
            const ushort* bb = (kk < 4) ? reg1 : reg0;
            const int hb = (kk & 3) * 32 + quad * 8;
#pragma unroll
            for (int nt = 0; nt < 4; ++nt) {
                short8 b2 = *reinterpret_cast<const short8*>(
                    &bb[(sh2 * 64 + nt * 16 + l15) * 136 + hb]);
                acc2[0][nt] = __builtin_amdgcn_mfma_f32_16x16x32_bf16(a20, b2, acc2[0][nt], 0, 0, 0);
                acc2[1][nt] = __builtin_amdgcn_mfma_f32_16x16x32_bf16(a21, b2, acc2[1][nt], 0, 0, 0);
            }
        }
        __syncthreads();   // B3: cur reads done, mp visible (Ps overwrites cur)

        // ---- P4: Ps write (f32) + Mstate ----
#pragma unroll
        for (int mt = 0; mt < 2; ++mt)
#pragma unroll
            for (int nt = 0; nt < 4; ++nt)
                *reinterpret_cast<f32x4*>(
                    &Ps[(sh2 * 64 + nt * 16 + l15) * 136 + dg * 32 + mt * 16 + quad * 4]) =
                    acc2[mt][nt];
        if (tid < HH) {
            float Mfull = a64 * mp[tid] + mp[256 + tid] + mbv;
            Mstate[((size_t)b * NC + q * NCH + ci) * HH + tid] = Mfull;
        }
        __syncthreads();   // B4: Ps visible

        // ---- P5: anti-diagonal partials ----
        float part = 0.0f;
        {
            int k = tid & 127, g = tid >> 7;
#pragma unroll 8
            for (int i = 0; i < 32; ++i) {
                int s = g * 32 + i;
                int d = k - s;
                float v = Ps[s * 136 + (d < 0 ? 0 : d)];
                part += (d >= 0) ? v : 0.0f;
            }
            if (g > 0) psum[g * 128 + k] = part;
        }
        __syncthreads();   // B5: psum visible; Ps reads done

        // ---- P6: y write (merged with next chunk's P0) ----
        if (tid < 128) {
            float y = part + psum[128 + tid] + psum[256 + tid] + psum[384 + tid];
            ypart[(size_t)b * TT + q * 512 + ci * 128 + tid] = y;
        }
    }
}

// ---------------- K2: chunk-level state chain (in-place) ----------------
__global__ __launch_bounds__(256) void k2_chain(
    float* __restrict__ Mstate, const float* __restrict__ ApowT)
{
    int idx = blockIdx.x * 256 + threadIdx.x;   // over BB*HH
    int b = idx >> 8, h = idx & 255;
    float aL = ApowT[127 * 256 + h];            // a^128
    float M = 0.0f;
#pragma unroll
    for (int c = 0; c < NC; ++c) {
        size_t o = ((size_t)b * NC + c) * HH + h;
        float prev = Mstate[o];
        Mstate[o] = M;                          // Minit for chunk c
        M = fmaf(aL, M, prev);
    }
}

// ---------------- K3: fixup + bias + sigmoid, 8 chunks/block ----------------
__global__ __launch_bounds__(256) void k3_out(
    const float* __restrict__ ypart, const float* __restrict__ Mstate,
    const float* __restrict__ ApowT, const float* __restrict__ Wo,
    const float* __restrict__ bo, const float* __restrict__ ybias,
    float* __restrict__ out)
{
    __shared__ __align__(16) float wc[8 * 256];
    const int blk = blockIdx.x;
    const int b = blk >> 2, cg = blk & 3;       // chunks cg*8 .. cg*8+7
    const int tid = threadIdx.x;
#pragma unroll
    for (int cc = 0; cc < 8; ++cc)
        wc[cc * 256 + tid] =
            Wo[tid] * Mstate[((size_t)b * NC + cg * 8 + cc) * HH + tid];
    __syncthreads();

    const int k = tid & 127, hi = tid >> 7;
    float corr[4] = {0.f, 0.f, 0.f, 0.f};
    const float* ap = &ApowT[k * 256];
#pragma unroll 4
    for (int h4 = 0; h4 < 64; ++h4) {
        float4 av = *reinterpret_cast<const float4*>(&ap[h4 * 4]);
#pragma unroll
        for (int c4 = 0; c4 < 4; ++c4) {
            float4 wv = *reinterpret_cast<const float4*>(&wc[(hi * 4 + c4) * 256 + h4 * 4]);
            corr[c4] += wv.x * av.x + wv.y * av.y + wv.z * av.z + wv.w * av.w;
        }
    }
    const float bk = ybias[k] + bo[0];
#pragma unroll
    for (int c4 = 0; c4 < 4; ++c4) {
        int c = cg * 8 + hi * 4 + c4;
        size_t t = (size_t)b * TT + (size_t)c * LC + k;
        float z = ypart[t] + corr[c4] + bk;
        out[t] = 1.0f / (1.0f + expf(-z));
    }
}

extern "C" void kernel_launch(void* const* d_in, const int* in_sizes, int n_in,
                              void* d_out, int out_size, void* d_ws, size_t ws_size,
                              hipStream_t stream) {
    const float* x   = (const float*)d_in[0];
    const float* Wd  = (const float*)d_in[1];
    const float* bd  = (const float*)d_in[2];
    const float* Wo  = (const float*)d_in[3];
    const float* bo  = (const float*)d_in[4];
    const float* tau = (const float*)d_in[5];
    float* out = (float*)d_out;

    float* ws = (float*)d_ws;
    float*  ypart  = ws;                          // 262144
    float*  Mstate = ws + 262144;                 // 524288
    float*  ApowT  = ws + 786432;                 // 32768: ApowT[k][h] = a_h^(k+1)
    float*  alphas = ws + 819200;                 // 256
    float*  mb     = ws + 819456;                 // 256
    float*  ybias  = ws + 819712;                 // 128
    ushort* Wdb    = (ushort*)(ws + 819840);      // 32768 u16
    ushort* Vt     = (ushort*)(ws + 836224);      // 32768 u16: Vt[d][h]

    k0_tables<<<128, 256, 0, stream>>>(Wd, bd, Wo, tau, Wdb, Vt, ApowT, alphas, mb, ybias);
    k1_fused<<<BB * NC / NCH, 512, 0, stream>>>(x, Wdb, Vt, alphas, mb, ApowT, ypart, Mstate);
    k2_chain<<<BB * HH / 256, 256, 0, stream>>>(Mstate, ApowT);
    k3_out<<<BB * 4, 256, 0, stream>>>(ypart, Mstate, ApowT, Wo, bo, ybias, out);
}